// Round 12
// baseline (497.098 us; speedup 1.0000x reference)
//
#include <hip/hip_runtime.h>
#include <cstdint>

// Problem constants (match reference)
#define B_    8
#define CIN   3
#define NPTS  32768            // N
#define TOT   (B_*NPTS)        // 262144 nodes
#define COUT  128
#define NE    4194304          // edges
#define NF    12               // K*CIN features per node
#define NMOM  90
#define BN_EPS 1e-5f

#define NBKT  256              // buckets
#define BKSZ  1024             // nodes per bucket (TOT/NBKT)
#define MTILE 4096             // edges per scatter tile (mega)
#define MEPT  4                // edges per thread (MTILE/1024)
#define CAPS  18432            // src-bucket region capacity
#define CAPD  18432            // dst-bucket region capacity (verified r7-r11)

// ===================== shared-memory union for mega phases ==================
struct SMemSc {
    int2 sorted2[MTILE];             // 32 KB (phase A aliases as int[])
    int  lhist[NBKT], lbase[NBKT], cnt2[NBKT], gbase[NBKT], wt[16];
    unsigned char sbk[MTILE];        // 4 KB
};
struct SMemDd { float acc[BKSZ]; };
struct SMemPr { float acc[BKSZ * 3]; };
struct SMemMp { float L[1024 * 13]; float R[16][96]; float sm[96]; };
struct SMemOt { float sw[NF * COUT]; float sb[COUT]; };
union SMemU { SMemSc sc; SMemDd dd; SMemPr pr; SMemMp mp; SMemOt ot; };

// ===================== grid barrier (normal launch, self-cleaning) ==========
__device__ __forceinline__ void gridbar(int* bar, int nblk) {
    __syncthreads();
    if (threadIdx.x == 0) {
        __threadfence();
        int g = __hip_atomic_load(bar + 1, __ATOMIC_RELAXED, __HIP_MEMORY_SCOPE_AGENT);
        if (atomicAdd(bar, 1) == nblk - 1) {
            __hip_atomic_store(bar, 0, __ATOMIC_RELAXED, __HIP_MEMORY_SCOPE_AGENT);
            __threadfence();
            atomicAdd(bar + 1, 1);
        } else {
            while (__hip_atomic_load(bar + 1, __ATOMIC_RELAXED, __HIP_MEMORY_SCOPE_AGENT) == g) {
                __builtin_amdgcn_s_sleep(1);
            }
        }
        __threadfence();
    }
    __syncthreads();
}

// ===================== init cursors + barrier state =========================
__global__ __launch_bounds__(256) void k_binit(int* __restrict__ gp_s,
                                               int* __restrict__ gp_d,
                                               int* __restrict__ bar,
                                               int* __restrict__ done) {
    int t = threadIdx.x;
    gp_s[t] = t * CAPS;
    gp_d[t] = t * CAPD;
    if (t < 2) bar[t] = 0;
    if (t == 2) *done = 0;
}

// ===================== prop phase body ======================================
__device__ __forceinline__ void prop_phase(float* acc, const int* gp_d,
                                           const int2* binned_d,
                                           const float4* tin, const float4* tprev,
                                           float4* tout, float scale, int b, int t) {
    acc[t] = 0.f; acc[t + 1024] = 0.f; acc[t + 2048] = 0.f;
    __syncthreads();
    const int b0 = b * CAPD, b1 = gp_d[b];
    for (int i = b0 + t; i < b1; i += 1024) {
        int2 r = binned_d[i];
        int s  = r.x & 0x3FFFF;
        int dl = ((unsigned)r.x) >> 18;
        float4 ts = tin[s];
        float f = __int_as_float(r.y) * ts.w;     // w * dis[s]
        atomicAdd(&acc[dl * 3 + 0], f * ts.x);
        atomicAdd(&acc[dl * 3 + 1], f * ts.y);
        atomicAdd(&acc[dl * 3 + 2], f * ts.z);
    }
    __syncthreads();
    int n = b * BKSZ + t;
    float dn = tin[n].w;
    float m = -scale * dn;
    float r0 = m * acc[t * 3 + 0];
    float r1 = m * acc[t * 3 + 1];
    float r2 = m * acc[t * 3 + 2];
    if (tprev) {
        float4 tp = tprev[n];
        r0 -= tp.x; r1 -= tp.y; r2 -= tp.z;
    }
    tout[n] = make_float4(r0, r1, r2, dn);
}

__device__ __forceinline__ void decode_pair(int o, int& A, int& Bb) {
    if (o < 12) { A = o; Bb = 12; return; }
    int p = o - 12, base = 0; A = 0; Bb = 0;
#pragma unroll
    for (int aa = 0; aa < 12; ++aa) {
        int len = 12 - aa;
        bool in = (p >= base) && (p < base + len);
        if (in) { A = aa; Bb = aa + (p - base); }
        base += len;
    }
}

// ===================== the mega-kernel ======================================
__global__ __launch_bounds__(1024, 4) void k_mega(
        const int* __restrict__ src, const int* __restrict__ dst,
        const float* __restrict__ ew, const float* __restrict__ x,
        const float* __restrict__ weight, const float* __restrict__ bias,
        const float* __restrict__ gamma, const float* __restrict__ beta,
        int* __restrict__ gp_s, int* __restrict__ gp_d,
        int* __restrict__ binned_s, int2* __restrict__ binned_d,
        float4* __restrict__ tx0, float4* __restrict__ tx1,
        float4* __restrict__ tx2, float4* __restrict__ tx3,
        float* __restrict__ mom, float* __restrict__ wp, float* __restrict__ bp,
        int* __restrict__ bar, float* __restrict__ out) {
    __shared__ SMemU u;
    const int t = threadIdx.x, b = blockIdx.x;
    const int lane = t & 63, wv = t >> 6;

    // ---------------- phase 1: dual scatter (4 tiles of 4096 edges) --------
    for (int it = 0; it < 4; ++it) {
        const int tile = b * 4 + it;
        int es[MEPT], ed[MEPT]; float ef[MEPT]; bool va[MEPT];
        const int base = tile * MTILE + t;
#pragma unroll
        for (int k = 0; k < MEPT; ++k) {
            int e = base + k * 1024;
            es[k] = src[e]; ed[k] = dst[e]; ef[k] = ew[e];
            va[k] = (es[k] != ed[k]) && (ef[k] != 0.0f);
        }
        // ---- phase A: bin by src ----
        if (t < NBKT) { u.sc.lhist[t] = 0; u.sc.cnt2[t] = 0; }
        __syncthreads();
#pragma unroll
        for (int k = 0; k < MEPT; ++k)
            if (va[k]) atomicAdd(&u.sc.lhist[es[k] >> 10], 1);
        __syncthreads();
        int v = 0, inc = 0;
        if (t < NBKT) {
            v = u.sc.lhist[t]; inc = v;
#pragma unroll
            for (int d = 1; d < 64; d <<= 1) {
                int uu = __shfl_up(inc, d, 64);
                if (lane >= d) inc += uu;
            }
            if (lane == 63) u.sc.wt[wv] = inc;
        }
        __syncthreads();
        if (t < NBKT) {
            int pre = 0;
#pragma unroll
            for (int k = 0; k < 4; ++k) if (k < wv) pre += u.sc.wt[k];
            u.sc.lbase[t] = pre + inc - v;
            u.sc.gbase[t] = atomicAdd(gp_s + t, v);
        }
        __syncthreads();
        int* sortedI = (int*)u.sc.sorted2;
#pragma unroll
        for (int k = 0; k < MEPT; ++k) {
            if (va[k]) {
                int bb = es[k] >> 10;
                int p = atomicAdd(&u.sc.cnt2[bb], 1);
                int idx = u.sc.lbase[bb] + p;
                sortedI[idx] = (__float_as_int(ef[k]) & 0xFFFFFC00) | (es[k] & 1023);
                u.sc.sbk[idx] = (unsigned char)bb;
            }
        }
        __syncthreads();
        {
            int tot = u.sc.lbase[NBKT - 1] + u.sc.lhist[NBKT - 1];
            for (int i = t; i < tot; i += 1024) {
                int bb = u.sc.sbk[i];
                binned_s[(size_t)u.sc.gbase[bb] + (i - u.sc.lbase[bb])] = sortedI[i];
            }
        }
        __syncthreads();
        // ---- phase B: bin by dst ----
        if (t < NBKT) { u.sc.lhist[t] = 0; u.sc.cnt2[t] = 0; }
        __syncthreads();
#pragma unroll
        for (int k = 0; k < MEPT; ++k)
            if (va[k]) atomicAdd(&u.sc.lhist[ed[k] >> 10], 1);
        __syncthreads();
        v = 0; inc = 0;
        if (t < NBKT) {
            v = u.sc.lhist[t]; inc = v;
#pragma unroll
            for (int d = 1; d < 64; d <<= 1) {
                int uu = __shfl_up(inc, d, 64);
                if (lane >= d) inc += uu;
            }
            if (lane == 63) u.sc.wt[wv] = inc;
        }
        __syncthreads();
        if (t < NBKT) {
            int pre = 0;
#pragma unroll
            for (int k = 0; k < 4; ++k) if (k < wv) pre += u.sc.wt[k];
            u.sc.lbase[t] = pre + inc - v;
            u.sc.gbase[t] = atomicAdd(gp_d + t, v);
        }
        __syncthreads();
#pragma unroll
        for (int k = 0; k < MEPT; ++k) {
            if (va[k]) {
                int bb = ed[k] >> 10;
                int p = atomicAdd(&u.sc.cnt2[bb], 1);
                int idx = u.sc.lbase[bb] + p;
                u.sc.sorted2[idx] = make_int2(es[k] | ((ed[k] & 1023) << 18),
                                              __float_as_int(ef[k]));
                u.sc.sbk[idx] = (unsigned char)bb;
            }
        }
        __syncthreads();
        {
            int tot = u.sc.lbase[NBKT - 1] + u.sc.lhist[NBKT - 1];
            for (int i = t; i < tot; i += 1024) {
                int bb = u.sc.sbk[i];
                binned_d[(size_t)u.sc.gbase[bb] + (i - u.sc.lbase[bb])] = u.sc.sorted2[i];
            }
        }
        __syncthreads();
    }
    gridbar(bar, NBKT);

    // ---------------- phase 2: deg reduce + dis + pack tx0 -----------------
    {
        u.dd.acc[t] = 0.f;
        __syncthreads();
        int b0 = b * CAPS, b1 = gp_s[b];
        for (int i = b0 + t; i < b1; i += 1024) {
            int r = binned_s[i];
            atomicAdd(&u.dd.acc[r & 1023], __int_as_float(r & 0xFFFFFC00));
        }
        __syncthreads();
        float v = u.dd.acc[t];
        float dn = (v > 0.f) ? rsqrtf(fmaxf(v, 1e-12f)) : 0.f;
        int n = b * BKSZ + t;
        int batch = n >> 15, nn = n & (NPTS - 1);
        const float* xb = x + (size_t)batch * CIN * NPTS + nn;
        tx0[n] = make_float4(xb[0], xb[NPTS], xb[2 * NPTS], dn);
    }
    gridbar(bar, NBKT);

    // ---------------- phases 3-5: Chebyshev props --------------------------
    prop_phase(u.pr.acc, gp_d, binned_d, tx0, nullptr, tx1, 1.0f, b, t);
    gridbar(bar, NBKT);
    prop_phase(u.pr.acc, gp_d, binned_d, tx1, tx0,     tx2, 2.0f, b, t);
    gridbar(bar, NBKT);
    prop_phase(u.pr.acc, gp_d, binned_d, tx2, tx1,     tx3, 2.0f, b, t);
    gridbar(bar, NBKT);

    // ---------------- phase 6: moment partials -----------------------------
    {
        int a1, b1p, a2 = 12, b2 = 12;
        decode_pair(lane, a1, b1p);
        if (lane < 26) decode_pair(64 + lane, a2, b2);
        int node = b * 1024 + t;
        float* Ld = &u.mp.L[t * 13];
        float4 a = tx0[node]; Ld[0] = a.x; Ld[1]  = a.y; Ld[2]  = a.z;
        float4 c = tx1[node]; Ld[3] = c.x; Ld[4]  = c.y; Ld[5]  = c.z;
        float4 d = tx2[node]; Ld[6] = d.x; Ld[7]  = d.y; Ld[8]  = d.z;
        float4 e = tx3[node]; Ld[9] = e.x; Ld[10] = e.y; Ld[11] = e.z;
        Ld[12] = 1.0f;
        __syncthreads();
        float acc1 = 0.f, acc2 = 0.f;
        const int nb = wv * 64;
#pragma unroll 4
        for (int i = 0; i < 64; ++i) {
            const float* Ln = &u.mp.L[(nb + i) * 13];
            acc1 += Ln[a1] * Ln[b1p];
            if (lane < 26) acc2 += Ln[a2] * Ln[b2];
        }
        u.mp.R[wv][lane] = acc1;
        if (lane < 26) u.mp.R[wv][64 + lane] = acc2;
        __syncthreads();
        if (t < NMOM) {
            float s = 0.f;
#pragma unroll
            for (int w2 = 0; w2 < 16; ++w2) s += u.mp.R[w2][t];
            mom[b * 96 + t] = s;
        }
    }
    gridbar(bar, NBKT);

    // ---------------- phase 7: BN fold (block 0 only) ----------------------
    if (b == 0) {
        if (t < NMOM) {
            float s = 0.f;
            for (int bb = 0; bb < NBKT; ++bb) s += mom[bb * 96 + t];
            u.mp.sm[t] = s;
        }
        __syncthreads();
        if (t < COUT) {
            int c = t;
            float wvv[NF];
#pragma unroll
            for (int f = 0; f < NF; ++f) wvv[f] = weight[f * COUT + c];
            const float inv = 1.0f / (float)TOT;
            float mw = 0.0f;
#pragma unroll
            for (int a = 0; a < NF; ++a) mw += (u.mp.sm[a] * inv) * wvv[a];
            float q = 0.0f;
            int idx = NF;
#pragma unroll
            for (int a = 0; a < NF; ++a) {
#pragma unroll
                for (int b2 = a; b2 < NF; ++b2) {
                    float S2 = u.mp.sm[idx++] * inv;
                    q += ((a == b2) ? 1.0f : 2.0f) * wvv[a] * wvv[b2] * S2;
                }
            }
            float bc   = bias[c];
            float mean = mw + bc;
            float var  = q - mw * mw;
            float sc   = gamma[c] * rsqrtf(var + BN_EPS);
            float sh   = (bc - mean) * sc + beta[c];
#pragma unroll
            for (int f = 0; f < NF; ++f) wp[f * COUT + c] = wvv[f] * sc;
            bp[c] = sh;
        }
    }
    gridbar(bar, NBKT);

    // ---------------- phase 8: fused linear + BN + ReLU + transpose --------
    {
        for (int j = t; j < NF * COUT; j += 1024) u.ot.sw[j] = wp[j];
        if (t < COUT) u.ot.sb[t] = bp[t];
        __syncthreads();
        int n = b * 1024 + t;
        int batch = n >> 15, nn = n & (NPTS - 1);
        float tf[NF];
        float4 a = tx0[n]; tf[0] = a.x; tf[1]  = a.y; tf[2]  = a.z;
        float4 c = tx1[n]; tf[3] = c.x; tf[4]  = c.y; tf[5]  = c.z;
        float4 d = tx2[n]; tf[6] = d.x; tf[7]  = d.y; tf[8]  = d.z;
        float4 e = tx3[n]; tf[9] = e.x; tf[10] = e.y; tf[11] = e.z;
        float* o = out + (size_t)batch * COUT * NPTS + nn;
#pragma unroll 4
        for (int c2 = 0; c2 < COUT; ++c2) {
            float acc = u.ot.sb[c2];
#pragma unroll
            for (int f = 0; f < NF; ++f) acc += tf[f] * u.ot.sw[f * COUT + c2];
            o[(size_t)c2 * NPTS] = fmaxf(acc, 0.0f);
        }
    }
}

// ===================== fallback (r8-style 8-kernel path) ====================
__global__ __launch_bounds__(256) void k_scatter2(const int* __restrict__ src,
                                                  const int* __restrict__ dst,
                                                  const float* __restrict__ ew,
                                                  int* __restrict__ gp_s,
                                                  int* __restrict__ gp_d,
                                                  int* __restrict__ binned_s,
                                                  int2* __restrict__ binned_d) {
    __shared__ int lhist[NBKT], lbase[NBKT], cnt2[NBKT], gbase[NBKT];
    __shared__ int2 sorted2[2048];
    __shared__ unsigned char sbk[2048];
    __shared__ int wt[4];
    const int t = threadIdx.x, lane = t & 63, wv = t >> 6;
    int es[8], ed[8]; float ef[8]; bool va[8];
    const int base = blockIdx.x * 2048 + t;
#pragma unroll
    for (int k = 0; k < 8; ++k) {
        int e = base + k * 256;
        es[k] = src[e]; ed[k] = dst[e]; ef[k] = ew[e];
        va[k] = (es[k] != ed[k]) && (ef[k] != 0.0f);
    }
    lhist[t] = 0; cnt2[t] = 0;
    __syncthreads();
#pragma unroll
    for (int k = 0; k < 8; ++k)
        if (va[k]) atomicAdd(&lhist[es[k] >> 10], 1);
    __syncthreads();
    {
        int v = lhist[t], inc = v;
#pragma unroll
        for (int d = 1; d < 64; d <<= 1) {
            int uu = __shfl_up(inc, d, 64);
            if (lane >= d) inc += uu;
        }
        if (lane == 63) wt[wv] = inc;
        __syncthreads();
        int pre = 0;
#pragma unroll
        for (int k = 0; k < 4; ++k) if (k < wv) pre += wt[k];
        lbase[t] = pre + inc - v;
        gbase[t] = atomicAdd(gp_s + t, v);
    }
    __syncthreads();
    int* sortedI = (int*)sorted2;
#pragma unroll
    for (int k = 0; k < 8; ++k) {
        if (va[k]) {
            int bb = es[k] >> 10;
            int p = atomicAdd(&cnt2[bb], 1);
            int idx = lbase[bb] + p;
            sortedI[idx] = (__float_as_int(ef[k]) & 0xFFFFFC00) | (es[k] & 1023);
            sbk[idx] = (unsigned char)bb;
        }
    }
    __syncthreads();
    {
        int tot = lbase[NBKT - 1] + lhist[NBKT - 1];
        for (int i = t; i < tot; i += 256) {
            int bb = sbk[i];
            binned_s[(size_t)gbase[bb] + (i - lbase[bb])] = sortedI[i];
        }
    }
    __syncthreads();
    lhist[t] = 0; cnt2[t] = 0;
    __syncthreads();
#pragma unroll
    for (int k = 0; k < 8; ++k)
        if (va[k]) atomicAdd(&lhist[ed[k] >> 10], 1);
    __syncthreads();
    {
        int v = lhist[t], inc = v;
#pragma unroll
        for (int d = 1; d < 64; d <<= 1) {
            int uu = __shfl_up(inc, d, 64);
            if (lane >= d) inc += uu;
        }
        if (lane == 63) wt[wv] = inc;
        __syncthreads();
        int pre = 0;
#pragma unroll
        for (int k = 0; k < 4; ++k) if (k < wv) pre += wt[k];
        lbase[t] = pre + inc - v;
        gbase[t] = atomicAdd(gp_d + t, v);
    }
    __syncthreads();
#pragma unroll
    for (int k = 0; k < 8; ++k) {
        if (va[k]) {
            int bb = ed[k] >> 10;
            int p = atomicAdd(&cnt2[bb], 1);
            int idx = lbase[bb] + p;
            sorted2[idx] = make_int2(es[k] | ((ed[k] & 1023) << 18),
                                     __float_as_int(ef[k]));
            sbk[idx] = (unsigned char)bb;
        }
    }
    __syncthreads();
    {
        int tot = lbase[NBKT - 1] + lhist[NBKT - 1];
        for (int i = t; i < tot; i += 256) {
            int bb = sbk[i];
            binned_d[(size_t)gbase[bb] + (i - lbase[bb])] = sorted2[i];
        }
    }
}

__global__ __launch_bounds__(1024) void k_degdispack(const int* __restrict__ gp_s,
                                                     const int* __restrict__ binned_s,
                                                     const float* __restrict__ x,
                                                     float4* __restrict__ tx0) {
    __shared__ float acc[BKSZ];
    int t = threadIdx.x, b = blockIdx.x;
    acc[t] = 0.f;
    __syncthreads();
    int b0 = b * CAPS, b1 = gp_s[b];
    for (int i = b0 + t; i < b1; i += 1024) {
        int r = binned_s[i];
        atomicAdd(&acc[r & 1023], __int_as_float(r & 0xFFFFFC00));
    }
    __syncthreads();
    float v = acc[t];
    float dn = (v > 0.f) ? rsqrtf(fmaxf(v, 1e-12f)) : 0.f;
    int n = b * BKSZ + t;
    int batch = n >> 15, nn = n & (NPTS - 1);
    const float* xb = x + (size_t)batch * CIN * NPTS + nn;
    tx0[n] = make_float4(xb[0], xb[NPTS], xb[2 * NPTS], dn);
}

__global__ __launch_bounds__(1024) void k_prop(const int* __restrict__ gp_d,
                                               const int2* __restrict__ binned_d,
                                               const float4* __restrict__ tin,
                                               const float4* __restrict__ tprev,
                                               float4* __restrict__ tout,
                                               float scale) {
    __shared__ float acc[BKSZ * 3];
    prop_phase(acc, gp_d, binned_d, tin, tprev, tout, scale, blockIdx.x, threadIdx.x);
}

__global__ __launch_bounds__(256) void k_momprep(const float4* __restrict__ tx0,
                                                 const float4* __restrict__ tx1,
                                                 const float4* __restrict__ tx2,
                                                 const float4* __restrict__ tx3,
                                                 float* __restrict__ mom,
                                                 int* __restrict__ done,
                                                 const float* __restrict__ weight,
                                                 const float* __restrict__ bias,
                                                 const float* __restrict__ gamma,
                                                 const float* __restrict__ beta,
                                                 float* __restrict__ wp,
                                                 float* __restrict__ bp) {
    __shared__ float L[256 * 13];
    __shared__ float R[4][96];
    __shared__ int amLast;
    const int tid = threadIdx.x, lane = tid & 63, w = tid >> 6;
    int a1, b1, a2 = 12, b2 = 12;
    decode_pair(lane, a1, b1);
    if (lane < 26) decode_pair(64 + lane, a2, b2);
    float acc1 = 0.0f, acc2 = 0.0f;
    for (int t = 0; t < 4; ++t) {
        int node = (blockIdx.x * 4 + t) * 256 + tid;
        __syncthreads();
        float* Ld = &L[tid * 13];
        float4 a = tx0[node]; Ld[0] = a.x; Ld[1]  = a.y; Ld[2]  = a.z;
        float4 c = tx1[node]; Ld[3] = c.x; Ld[4]  = c.y; Ld[5]  = c.z;
        float4 d = tx2[node]; Ld[6] = d.x; Ld[7]  = d.y; Ld[8]  = d.z;
        float4 e = tx3[node]; Ld[9] = e.x; Ld[10] = e.y; Ld[11] = e.z;
        Ld[12] = 1.0f;
        __syncthreads();
        const int nb = w * 64;
#pragma unroll 4
        for (int i = 0; i < 64; ++i) {
            const float* Ln = &L[(nb + i) * 13];
            acc1 += Ln[a1] * Ln[b1];
            if (lane < 26) acc2 += Ln[a2] * Ln[b2];
        }
    }
    R[w][lane] = acc1;
    if (lane < 26) R[w][64 + lane] = acc2;
    __syncthreads();
    if (tid < NMOM)
        mom[blockIdx.x * 96 + tid] = R[0][tid] + R[1][tid] + R[2][tid] + R[3][tid];
    __threadfence();
    __syncthreads();
    if (tid == 0) amLast = (atomicAdd(done, 1) == NBKT - 1) ? 1 : 0;
    __syncthreads();
    if (!amLast) return;
    __threadfence();
    __shared__ float sm[NMOM];
    if (tid < NMOM) {
        float s = 0.f;
        for (int b = 0; b < NBKT; ++b) s += mom[b * 96 + tid];
        sm[tid] = s;
    }
    __syncthreads();
    if (tid >= COUT) return;
    int c = tid;
    float wvv[NF];
#pragma unroll
    for (int f = 0; f < NF; ++f) wvv[f] = weight[f * COUT + c];
    const float inv = 1.0f / (float)TOT;
    float mw = 0.0f;
#pragma unroll
    for (int a = 0; a < NF; ++a) mw += (sm[a] * inv) * wvv[a];
    float q = 0.0f;
    int idx = NF;
#pragma unroll
    for (int a = 0; a < NF; ++a) {
#pragma unroll
        for (int b = a; b < NF; ++b) {
            float S2 = sm[idx++] * inv;
            q += ((a == b) ? 1.0f : 2.0f) * wvv[a] * wvv[b] * S2;
        }
    }
    float bc   = bias[c];
    float mean = mw + bc;
    float var  = q - mw * mw;
    float sc   = gamma[c] * rsqrtf(var + BN_EPS);
    float sh   = (bc - mean) * sc + beta[c];
#pragma unroll
    for (int f = 0; f < NF; ++f) wp[f * COUT + c] = wvv[f] * sc;
    bp[c] = sh;
}

__global__ __launch_bounds__(256) void k_out(const float4* __restrict__ tx0,
                                             const float4* __restrict__ tx1,
                                             const float4* __restrict__ tx2,
                                             const float4* __restrict__ tx3,
                                             const float* __restrict__ wp,
                                             const float* __restrict__ bp,
                                             float* __restrict__ out) {
    __shared__ float sw[NF * COUT];
    __shared__ float sb[COUT];
    for (int j = threadIdx.x; j < NF * COUT; j += 256) sw[j] = wp[j];
    if (threadIdx.x < COUT) sb[threadIdx.x] = bp[threadIdx.x];
    __syncthreads();
    int i = blockIdx.x * 256 + threadIdx.x;
    int b = i >> 15;
    int n = i & (NPTS - 1);
    float tf[NF];
    float4 a = tx0[i]; tf[0] = a.x; tf[1]  = a.y; tf[2]  = a.z;
    float4 c = tx1[i]; tf[3] = c.x; tf[4]  = c.y; tf[5]  = c.z;
    float4 d = tx2[i]; tf[6] = d.x; tf[7]  = d.y; tf[8]  = d.z;
    float4 e = tx3[i]; tf[9] = e.x; tf[10] = e.y; tf[11] = e.z;
    float* o = out + (size_t)b * COUT * NPTS + n;
#pragma unroll 4
    for (int c2 = 0; c2 < COUT; ++c2) {
        float acc = sb[c2];
#pragma unroll
        for (int f = 0; f < NF; ++f) acc += tf[f] * sw[f * COUT + c2];
        o[(size_t)c2 * NPTS] = fmaxf(acc, 0.0f);
    }
}

// ===================== launcher =====================

extern "C" void kernel_launch(void* const* d_in, const int* in_sizes, int n_in,
                              void* d_out, int out_size, void* d_ws, size_t ws_size,
                              hipStream_t stream) {
    const float* x      = (const float*)d_in[0];
    const int*   ei     = (const int*)d_in[1];
    const float* ew     = (const float*)d_in[2];
    const float* weight = (const float*)d_in[3];
    const float* bias   = (const float*)d_in[4];
    const float* gamma  = (const float*)d_in[5];
    const float* beta   = (const float*)d_in[6];
    float* out = (float*)d_out;

    const int* src = ei;
    const int* dst = ei + NE;

    // workspace layout (4B words)
    const size_t od  = 0;                                  // binned_d int2[256*CAPD]
    const size_t os  = od  + (size_t)2 * NBKT * CAPD;      // binned_s int[256*CAPS]
    const size_t ot0 = os  + (size_t)NBKT * CAPS;          // tx0..3 float4[TOT]
    const size_t ot1 = ot0 + (size_t)4 * TOT;
    const size_t ot2 = ot1 + (size_t)4 * TOT;
    const size_t ot3 = ot2 + (size_t)4 * TOT;
    const size_t ogs = ot3 + (size_t)4 * TOT;              // gp_s[256]
    const size_t ogd = ogs + 256;                          // gp_d[256]
    const size_t omo = ogd + 256;                          // mom[256*96]
    const size_t owp = omo + 256 * 96;                     // wp[1536]
    const size_t obp = owp + 1536;                         // bp[128]
    const size_t odn = obp + 128;                          // done[1]
    const size_t oba = odn + 1;                            // bar[2]
    const size_t need = (oba + 2) * 4;

    int*    wsI      = (int*)d_ws;
    int2*   binned_d = (int2*)(wsI + od);
    int*    binned_s = wsI + os;
    float4* tx0      = (float4*)(wsI + ot0);
    float4* tx1      = (float4*)(wsI + ot1);
    float4* tx2      = (float4*)(wsI + ot2);
    float4* tx3      = (float4*)(wsI + ot3);
    int*    gp_s     = wsI + ogs;
    int*    gp_d     = wsI + ogd;
    float*  mom      = (float*)(wsI + omo);
    float*  wp       = (float*)(wsI + owp);
    float*  bp       = (float*)(wsI + obp);
    int*    done     = wsI + odn;
    int*    bar      = wsI + oba;

    dim3 blk(256);
    dim3 gT(TOT / 256);

    if (ws_size >= need) {
        k_binit<<<dim3(1), blk, 0, stream>>>(gp_s, gp_d, bar, done);
        k_mega<<<dim3(NBKT), dim3(1024), 0, stream>>>(
            src, dst, ew, x, weight, bias, gamma, beta,
            gp_s, gp_d, binned_s, binned_d,
            tx0, tx1, tx2, tx3, mom, wp, bp, bar, out);
    } else {
        k_binit     <<<dim3(1),    blk, 0, stream>>>(gp_s, gp_d, bar, done);
        k_scatter2  <<<dim3(NE / 2048), blk, 0, stream>>>(src, dst, ew, gp_s, gp_d,
                                                          binned_s, binned_d);
        k_degdispack<<<dim3(NBKT), dim3(1024), 0, stream>>>(gp_s, binned_s, x, tx0);
        k_prop<<<dim3(NBKT), dim3(1024), 0, stream>>>(gp_d, binned_d, tx0, nullptr, tx1, 1.0f);
        k_prop<<<dim3(NBKT), dim3(1024), 0, stream>>>(gp_d, binned_d, tx1, tx0,     tx2, 2.0f);
        k_prop<<<dim3(NBKT), dim3(1024), 0, stream>>>(gp_d, binned_d, tx2, tx1,     tx3, 2.0f);
        k_momprep<<<dim3(NBKT), blk, 0, stream>>>(tx0, tx1, tx2, tx3, mom, done,
                                                  weight, bias, gamma, beta, wp, bp);
        k_out    <<<gT, blk, 0, stream>>>(tx0, tx1, tx2, tx3, wp, bp, out);
    }
}

// Round 13
// 337.733 us; speedup vs baseline: 1.4719x; 1.4719x over previous
//
#include <hip/hip_runtime.h>
#include <cstdint>

// Problem constants (match reference)
#define B_    8
#define CIN   3
#define NPTS  32768            // N
#define TOT   (B_*NPTS)        // 262144 nodes
#define COUT  128
#define NE    4194304          // edges
#define NF    12               // K*CIN features per node
#define NMOM  90
#define BN_EPS 1e-5f

#define NBKT  256              // buckets
#define BKSZ  1024             // nodes per bucket (TOT/NBKT)
#define TILE2 4096             // edges per scatter block (r13: was 2048)
#define SCTH  512              // scatter threads (r13: was 256)
#define EPT2  8                // edges per thread (TILE2/SCTH)
#define CAPS  18432            // src-bucket region capacity (mean 16384 + 16 sigma)
#define CAPD  18432            // dst-bucket region capacity (verified r7-r12)

// ===================== init bucket cursors + done counter =====================
__global__ __launch_bounds__(256) void k_init(int* __restrict__ gp_s,
                                              int* __restrict__ gp_d,
                                              int* __restrict__ done) {
    int t = threadIdx.x;
    gp_s[t] = t * CAPS;
    gp_d[t] = t * CAPD;
    if (t == 0) *done = 0;
}

// ===================== combined scatter (one edge read, both outputs) =======
// src-binned record (int):  (w_bits & 0xFFFFFC00) | s_local     (for deg)
// dst-binned record (int2): {s | (d&1023)<<18, w_bits}          (for props)
// r13: 4096-edge tiles, 512 threads, ~40KB LDS -> 3 blocks/CU (24 waves)
__global__ __launch_bounds__(SCTH) void k_scatter2(const int* __restrict__ src,
                                                   const int* __restrict__ dst,
                                                   const float* __restrict__ ew,
                                                   int* __restrict__ gp_s,
                                                   int* __restrict__ gp_d,
                                                   int* __restrict__ binned_s,
                                                   int2* __restrict__ binned_d) {
    __shared__ int lhist[NBKT], lbase[NBKT], cnt2[NBKT], gbase[NBKT];
    __shared__ int2 sorted2[TILE2];          // 32 KB (phase A aliases as int[4096])
    __shared__ unsigned char sbk[TILE2];     // 4 KB
    __shared__ int wt[4];
    const int t = threadIdx.x, lane = t & 63, wv = t >> 6;

    int es[EPT2], ed[EPT2]; float ef[EPT2]; bool va[EPT2];
    const int base = blockIdx.x * TILE2 + t;
#pragma unroll
    for (int k = 0; k < EPT2; ++k) {
        int e = base + k * SCTH;
        es[k] = src[e]; ed[k] = dst[e]; ef[k] = ew[e];
        va[k] = (es[k] != ed[k]) && (ef[k] != 0.0f);
    }

    // ---------- phase A: bin by src ----------
    if (t < NBKT) { lhist[t] = 0; cnt2[t] = 0; }
    __syncthreads();
#pragma unroll
    for (int k = 0; k < EPT2; ++k)
        if (va[k]) atomicAdd(&lhist[es[k] >> 10], 1);
    __syncthreads();
    {
        int v = 0, inc = 0;
        if (t < NBKT) {
            v = lhist[t]; inc = v;
#pragma unroll
            for (int d = 1; d < 64; d <<= 1) {
                int u = __shfl_up(inc, d, 64);
                if (lane >= d) inc += u;
            }
            if (lane == 63) wt[wv] = inc;
        }
        __syncthreads();
        if (t < NBKT) {
            int pre = 0;
#pragma unroll
            for (int k = 0; k < 4; ++k) if (k < wv) pre += wt[k];
            lbase[t] = pre + inc - v;
            gbase[t] = atomicAdd(gp_s + t, v);
        }
    }
    __syncthreads();
    int* sortedI = (int*)sorted2;
#pragma unroll
    for (int k = 0; k < EPT2; ++k) {
        if (va[k]) {
            int b = es[k] >> 10;
            int p = atomicAdd(&cnt2[b], 1);
            int idx = lbase[b] + p;
            sortedI[idx] = (__float_as_int(ef[k]) & 0xFFFFFC00) | (es[k] & 1023);
            sbk[idx] = (unsigned char)b;
        }
    }
    __syncthreads();
    {
        int tot = lbase[NBKT - 1] + lhist[NBKT - 1];
        for (int i = t; i < tot; i += SCTH) {
            int b = sbk[i];
            binned_s[(size_t)gbase[b] + (i - lbase[b])] = sortedI[i];
        }
    }
    __syncthreads();

    // ---------- phase B: bin by dst ----------
    if (t < NBKT) { lhist[t] = 0; cnt2[t] = 0; }
    __syncthreads();
#pragma unroll
    for (int k = 0; k < EPT2; ++k)
        if (va[k]) atomicAdd(&lhist[ed[k] >> 10], 1);
    __syncthreads();
    {
        int v = 0, inc = 0;
        if (t < NBKT) {
            v = lhist[t]; inc = v;
#pragma unroll
            for (int d = 1; d < 64; d <<= 1) {
                int u = __shfl_up(inc, d, 64);
                if (lane >= d) inc += u;
            }
            if (lane == 63) wt[wv] = inc;
        }
        __syncthreads();
        if (t < NBKT) {
            int pre = 0;
#pragma unroll
            for (int k = 0; k < 4; ++k) if (k < wv) pre += wt[k];
            lbase[t] = pre + inc - v;
            gbase[t] = atomicAdd(gp_d + t, v);
        }
    }
    __syncthreads();
#pragma unroll
    for (int k = 0; k < EPT2; ++k) {
        if (va[k]) {
            int b = ed[k] >> 10;
            int p = atomicAdd(&cnt2[b], 1);
            int idx = lbase[b] + p;
            sorted2[idx] = make_int2(es[k] | ((ed[k] & 1023) << 18),
                                     __float_as_int(ef[k]));
            sbk[idx] = (unsigned char)b;
        }
    }
    __syncthreads();
    {
        int tot = lbase[NBKT - 1] + lhist[NBKT - 1];
        for (int i = t; i < tot; i += SCTH) {
            int b = sbk[i];
            binned_d[(size_t)gbase[b] + (i - lbase[b])] = sorted2[i];
        }
    }
}

// ====== deg reduce (LDS atomics) + dis + pack tx0 = {x0,x1,x2,dis} ==========
__global__ __launch_bounds__(1024) void k_degdispack(const int* __restrict__ gp_s,
                                                     const int* __restrict__ binned_s,
                                                     const float* __restrict__ x,
                                                     float4* __restrict__ tx0) {
    __shared__ float acc[BKSZ];
    int t = threadIdx.x, b = blockIdx.x;
    acc[t] = 0.f;
    __syncthreads();
    int b0 = b * CAPS, b1 = gp_s[b];
    for (int i = b0 + t; i < b1; i += 1024) {
        int r = binned_s[i];
        atomicAdd(&acc[r & 1023], __int_as_float(r & 0xFFFFFC00));
    }
    __syncthreads();
    float v = acc[t];
    float dn = (v > 0.f) ? rsqrtf(fmaxf(v, 1e-12f)) : 0.f;
    int n = b * BKSZ + t;
    int batch = n >> 15, nn = n & (NPTS - 1);
    const float* xb = x + (size_t)batch * CIN * NPTS + nn;
    tx0[n] = make_float4(xb[0], xb[NPTS], xb[2 * NPTS], dn);
}

// ====== LDS-atomic gather prop (r8-exact simple loop, 345us-verified) =======
// tout[n] = -scale*dis[n]*sum(w*dis_s*t_s) - tprev[n]
__global__ __launch_bounds__(1024) void k_prop(const int* __restrict__ gp_d,
                                               const int2* __restrict__ binned_d,
                                               const float4* __restrict__ tin,
                                               const float4* __restrict__ tprev,
                                               float4* __restrict__ tout,
                                               float scale) {
    __shared__ float acc[BKSZ * 3];
    int t = threadIdx.x, b = blockIdx.x;
    acc[t] = 0.f; acc[t + 1024] = 0.f; acc[t + 2048] = 0.f;
    __syncthreads();
    const int b0 = b * CAPD, b1 = gp_d[b];
    for (int i = b0 + t; i < b1; i += 1024) {
        int2 r = binned_d[i];
        int s  = r.x & 0x3FFFF;
        int dl = ((unsigned)r.x) >> 18;
        float4 ts = tin[s];
        float f = __int_as_float(r.y) * ts.w;     // w * dis[s]
        atomicAdd(&acc[dl * 3 + 0], f * ts.x);
        atomicAdd(&acc[dl * 3 + 1], f * ts.y);
        atomicAdd(&acc[dl * 3 + 2], f * ts.z);
    }
    __syncthreads();
    int n = b * BKSZ + t;
    float dn = tin[n].w;
    float m = -scale * dn;
    float r0 = m * acc[t * 3 + 0];
    float r1 = m * acc[t * 3 + 1];
    float r2 = m * acc[t * 3 + 2];
    if (tprev) {
        float4 tp = tprev[n];
        r0 -= tp.x; r1 -= tp.y; r2 -= tp.z;
    }
    tout[n] = make_float4(r0, r1, r2, dn);
}

// ===================== moments partials + last-block BN fold ================
__device__ __forceinline__ void decode_pair(int o, int& A, int& Bb) {
    if (o < 12) { A = o; Bb = 12; return; }
    int p = o - 12, base = 0; A = 0; Bb = 0;
#pragma unroll
    for (int aa = 0; aa < 12; ++aa) {
        int len = 12 - aa;
        bool in = (p >= base) && (p < base + len);
        if (in) { A = aa; Bb = aa + (p - base); }
        base += len;
    }
}

__global__ __launch_bounds__(256) void k_momprep(const float4* __restrict__ tx0,
                                                 const float4* __restrict__ tx1,
                                                 const float4* __restrict__ tx2,
                                                 const float4* __restrict__ tx3,
                                                 float* __restrict__ mom,
                                                 int* __restrict__ done,
                                                 const float* __restrict__ weight,
                                                 const float* __restrict__ bias,
                                                 const float* __restrict__ gamma,
                                                 const float* __restrict__ beta,
                                                 float* __restrict__ wp,
                                                 float* __restrict__ bp) {
    __shared__ float L[256 * 13];
    __shared__ float R[4][96];
    __shared__ int amLast;
    const int tid = threadIdx.x, lane = tid & 63, w = tid >> 6;

    int a1, b1, a2 = 12, b2 = 12;
    decode_pair(lane, a1, b1);
    if (lane < 26) decode_pair(64 + lane, a2, b2);

    float acc1 = 0.0f, acc2 = 0.0f;
    const int TPB = (TOT / 256) / 256;
    for (int t = 0; t < TPB; ++t) {
        int node = (blockIdx.x * TPB + t) * 256 + tid;
        __syncthreads();
        float* Ld = &L[tid * 13];
        float4 a = tx0[node]; Ld[0] = a.x; Ld[1]  = a.y; Ld[2]  = a.z;
        float4 c = tx1[node]; Ld[3] = c.x; Ld[4]  = c.y; Ld[5]  = c.z;
        float4 d = tx2[node]; Ld[6] = d.x; Ld[7]  = d.y; Ld[8]  = d.z;
        float4 e = tx3[node]; Ld[9] = e.x; Ld[10] = e.y; Ld[11] = e.z;
        Ld[12] = 1.0f;
        __syncthreads();
        const int nb = w * 64;
#pragma unroll 4
        for (int i = 0; i < 64; ++i) {
            const float* Ln = &L[(nb + i) * 13];
            acc1 += Ln[a1] * Ln[b1];
            if (lane < 26) acc2 += Ln[a2] * Ln[b2];
        }
    }
    R[w][lane] = acc1;
    if (lane < 26) R[w][64 + lane] = acc2;
    __syncthreads();
    if (tid < NMOM)
        mom[blockIdx.x * 96 + tid] = R[0][tid] + R[1][tid] + R[2][tid] + R[3][tid];

    // last-block folds BN
    __threadfence();
    __syncthreads();
    if (tid == 0) amLast = (atomicAdd(done, 1) == NBKT - 1) ? 1 : 0;
    __syncthreads();
    if (!amLast) return;
    __threadfence();

    __shared__ float sm[NMOM];
    if (tid < NMOM) {
        float s = 0.f;
        for (int b = 0; b < NBKT; ++b) s += mom[b * 96 + tid];
        sm[tid] = s;
    }
    __syncthreads();
    if (tid >= COUT) return;
    int c = tid;
    float wv[NF];
#pragma unroll
    for (int f = 0; f < NF; ++f) wv[f] = weight[f * COUT + c];

    const float inv = 1.0f / (float)TOT;
    float mw = 0.0f;
#pragma unroll
    for (int a = 0; a < NF; ++a) mw += (sm[a] * inv) * wv[a];

    float q = 0.0f;
    int idx = NF;
#pragma unroll
    for (int a = 0; a < NF; ++a) {
#pragma unroll
        for (int b = a; b < NF; ++b) {
            float S2 = sm[idx++] * inv;
            q += ((a == b) ? 1.0f : 2.0f) * wv[a] * wv[b] * S2;
        }
    }
    float bc   = bias[c];
    float mean = mw + bc;
    float var  = q - mw * mw;
    float sc   = gamma[c] * rsqrtf(var + BN_EPS);
    float sh   = (bc - mean) * sc + beta[c];
#pragma unroll
    for (int f = 0; f < NF; ++f) wp[f * COUT + c] = wv[f] * sc;
    bp[c] = sh;
}

// ===================== fused linear + BN + ReLU + transpose ==================
__global__ __launch_bounds__(256) void k_out(const float4* __restrict__ tx0,
                                             const float4* __restrict__ tx1,
                                             const float4* __restrict__ tx2,
                                             const float4* __restrict__ tx3,
                                             const float* __restrict__ wp,
                                             const float* __restrict__ bp,
                                             float* __restrict__ out) {
    __shared__ float sw[NF * COUT];
    __shared__ float sb[COUT];
    for (int j = threadIdx.x; j < NF * COUT; j += 256) sw[j] = wp[j];
    if (threadIdx.x < COUT) sb[threadIdx.x] = bp[threadIdx.x];
    __syncthreads();

    int i = blockIdx.x * 256 + threadIdx.x;
    int b = i >> 15;
    int n = i & (NPTS - 1);

    float t[NF];
    float4 a = tx0[i]; t[0] = a.x; t[1]  = a.y; t[2]  = a.z;
    float4 c = tx1[i]; t[3] = c.x; t[4]  = c.y; t[5]  = c.z;
    float4 d = tx2[i]; t[6] = d.x; t[7]  = d.y; t[8]  = d.z;
    float4 e = tx3[i]; t[9] = e.x; t[10] = e.y; t[11] = e.z;

    float* o = out + (size_t)b * COUT * NPTS + n;
#pragma unroll 4
    for (int c2 = 0; c2 < COUT; ++c2) {
        float acc = sb[c2];
#pragma unroll
        for (int f = 0; f < NF; ++f) acc += t[f] * sw[f * COUT + c2];
        o[(size_t)c2 * NPTS] = fmaxf(acc, 0.0f);
    }
}

// ===================== fallback (scatter-atomic) path ========================
__global__ __launch_bounds__(256) void k_deg_fb(const int* src, const int* dst,
                                                const float* ew, float* deg) {
    int e = blockIdx.x * 256 + threadIdx.x;
    int s = src[e], d = dst[e];
    float w = ew[e];
    if (s != d && w != 0.0f) atomicAdd(deg + s, w);
}
__global__ __launch_bounds__(256) void k_dis_fb(float* deg) {
    int i = blockIdx.x * 256 + threadIdx.x;
    float v = deg[i];
    deg[i] = (v > 0.0f) ? rsqrtf(fmaxf(v, 1e-12f)) : 0.0f;
}
__global__ __launch_bounds__(256) void k_pack_fb(const float* __restrict__ x,
                                                 const float* __restrict__ dis,
                                                 float4* __restrict__ tx0) {
    int i = blockIdx.x * 256 + threadIdx.x;
    int b = i >> 15, n = i & (NPTS - 1);
    const float* xb = x + (size_t)b * CIN * NPTS + n;
    tx0[i] = make_float4(xb[0], xb[NPTS], xb[2 * NPTS], dis[i]);
}
__global__ __launch_bounds__(256) void k_prop_fb(const int* src, const int* dst,
                                                 const float* ew, const float4* tin,
                                                 float* tacc) {
    int e = blockIdx.x * 256 + threadIdx.x;
    int s = src[e], d = dst[e];
    if (s == d) return;
    float w = ew[e];
    if (w == 0.0f) return;
    float4 ts = tin[s];
    float f = w * ts.w;
    atomicAdd(tacc + (size_t)d * 3 + 0, f * ts.x);
    atomicAdd(tacc + (size_t)d * 3 + 1, f * ts.y);
    atomicAdd(tacc + (size_t)d * 3 + 2, f * ts.z);
}
__global__ __launch_bounds__(256) void k_fin_fb(const float* __restrict__ tacc,
                                                const float4* __restrict__ tin,
                                                const float4* __restrict__ tprev,
                                                float4* __restrict__ tout,
                                                float scale) {
    int n = blockIdx.x * 256 + threadIdx.x;
    float dn = tin[n].w;
    float m = -scale * dn;
    float r0 = m * tacc[n * 3 + 0];
    float r1 = m * tacc[n * 3 + 1];
    float r2 = m * tacc[n * 3 + 2];
    if (tprev) {
        float4 tp = tprev[n];
        r0 -= tp.x; r1 -= tp.y; r2 -= tp.z;
    }
    tout[n] = make_float4(r0, r1, r2, dn);
}

// ===================== launcher =====================

extern "C" void kernel_launch(void* const* d_in, const int* in_sizes, int n_in,
                              void* d_out, int out_size, void* d_ws, size_t ws_size,
                              hipStream_t stream) {
    const float* x      = (const float*)d_in[0];
    const int*   ei     = (const int*)d_in[1];
    const float* ew     = (const float*)d_in[2];
    const float* weight = (const float*)d_in[3];
    const float* bias   = (const float*)d_in[4];
    const float* gamma  = (const float*)d_in[5];
    const float* beta   = (const float*)d_in[6];
    float* out = (float*)d_out;

    const int* src = ei;
    const int* dst = ei + NE;

    dim3 blk(256);
    dim3 gT(TOT / 256);      // 1024

    // workspace layout (4B words):
    const size_t od  = 0;                                  // binned_d int2[256*CAPD]
    const size_t os  = od  + (size_t)2 * NBKT * CAPD;      // binned_s int[256*CAPS]
    const size_t ot0 = os  + (size_t)NBKT * CAPS;          // tx0..3 float4[TOT]
    const size_t ot1 = ot0 + (size_t)4 * TOT;
    const size_t ot2 = ot1 + (size_t)4 * TOT;
    const size_t ot3 = ot2 + (size_t)4 * TOT;
    const size_t ogs = ot3 + (size_t)4 * TOT;              // gp_s[256]
    const size_t ogd = ogs + 256;                          // gp_d[256]
    const size_t omo = ogd + 256;                          // mom[256*96]
    const size_t owp = omo + 256 * 96;                     // wp[1536]
    const size_t obp = owp + 1536;                         // bp[128]
    const size_t odn = obp + 128;                          // done[1]
    const size_t need = (odn + 1) * 4;

    int*    wsI      = (int*)d_ws;
    int2*   binned_d = (int2*)(wsI + od);
    int*    binned_s = wsI + os;
    float4* tx0      = (float4*)(wsI + ot0);
    float4* tx1      = (float4*)(wsI + ot1);
    float4* tx2      = (float4*)(wsI + ot2);
    float4* tx3      = (float4*)(wsI + ot3);
    int*    gp_s     = wsI + ogs;
    int*    gp_d     = wsI + ogd;
    float*  mom      = (float*)(wsI + omo);
    float*  wp       = (float*)(wsI + owp);
    float*  bp       = (float*)(wsI + obp);
    int*    done     = wsI + odn;

    if (ws_size >= need) {
        k_init      <<<dim3(1),    blk, 0, stream>>>(gp_s, gp_d, done);
        k_scatter2  <<<dim3(NE / TILE2), dim3(SCTH), 0, stream>>>(src, dst, ew, gp_s, gp_d,
                                                                  binned_s, binned_d);
        k_degdispack<<<dim3(NBKT), dim3(1024), 0, stream>>>(gp_s, binned_s, x, tx0);

        k_prop<<<dim3(NBKT), dim3(1024), 0, stream>>>(gp_d, binned_d, tx0, nullptr, tx1, 1.0f);
        k_prop<<<dim3(NBKT), dim3(1024), 0, stream>>>(gp_d, binned_d, tx1, tx0,     tx2, 2.0f);
        k_prop<<<dim3(NBKT), dim3(1024), 0, stream>>>(gp_d, binned_d, tx2, tx1,     tx3, 2.0f);

        k_momprep<<<dim3(NBKT), blk, 0, stream>>>(tx0, tx1, tx2, tx3, mom, done,
                                                  weight, bias, gamma, beta, wp, bp);
        k_out    <<<gT, blk, 0, stream>>>(tx0, tx1, tx2, tx3, wp, bp, out);
    } else {
        // fallback scatter-atomic path (known-correct structure)
        dim3 gE(NE / 256);
        float* deg  = (float*)(wsI + od);                  // TOT
        float* tacc = deg + TOT;                           // 3*TOT

        (void)hipMemsetAsync(deg, 0, (size_t)4 * TOT * sizeof(float), stream);
        k_deg_fb <<<gE, blk, 0, stream>>>(src, dst, ew, deg);
        k_dis_fb <<<gT, blk, 0, stream>>>(deg);
        k_pack_fb<<<gT, blk, 0, stream>>>(x, deg, tx0);

        k_prop_fb<<<gE, blk, 0, stream>>>(src, dst, ew, tx0, tacc);
        k_fin_fb <<<gT, blk, 0, stream>>>(tacc, tx0, nullptr, tx1, 1.0f);
        (void)hipMemsetAsync(tacc, 0, (size_t)3 * TOT * sizeof(float), stream);
        k_prop_fb<<<gE, blk, 0, stream>>>(src, dst, ew, tx1, tacc);
        k_fin_fb <<<gT, blk, 0, stream>>>(tacc, tx1, tx0, tx2, 2.0f);
        (void)hipMemsetAsync(tacc, 0, (size_t)3 * TOT * sizeof(float), stream);
        k_prop_fb<<<gE, blk, 0, stream>>>(src, dst, ew, tx2, tacc);
        k_fin_fb <<<gT, blk, 0, stream>>>(tacc, tx2, tx1, tx3, 2.0f);

        k_momprep<<<dim3(NBKT), blk, 0, stream>>>(tx0, tx1, tx2, tx3, mom, done,
                                                  weight, bias, gamma, beta, wp, bp);
        k_out    <<<gT, blk, 0, stream>>>(tx0, tx1, tx2, tx3, wp, bp, out);
    }
}